// Round 20
// baseline (182.750 us; speedup 1.0000x reference)
//
#include <hip/hip_runtime.h>
#include <hip/hip_bf16.h>

#define B_    1024
#define C_    512
#define H_    8
#define D_    64
#define EPS_  1e-5f

typedef __attribute__((ext_vector_type(4))) float f32x4;
typedef __attribute__((ext_vector_type(8))) short bf16x8;
typedef __attribute__((ext_vector_type(8))) unsigned short u16x8;

__device__ __forceinline__ float bf2f(unsigned short h) {
    union { unsigned int u; float f; } c;
    c.u = ((unsigned int)h) << 16;
    return c.f;
}
__device__ __forceinline__ unsigned short f2bf(float f) {
    __hip_bfloat16 h = __float2bfloat16(f);
    return *reinterpret_cast<unsigned short*>(&h);
}

// LDS-only barrier: order ds ops across waves WITHOUT draining vmcnt.
#define KBAR() do { \
    asm volatile("s_waitcnt lgkmcnt(0)" ::: "memory"); \
    __builtin_amdgcn_s_barrier(); \
} while (0)

// ---------------------------------------------------------------------------
// K0 (merged): blocks 0..159 convert conv_w -> bf16 A-fragment order;
// blocks 160..207 build relB / relvA tables.
// ---------------------------------------------------------------------------
__global__ __launch_bounds__(256) void k0_prep(
    const float* __restrict__ w, const float* __restrict__ rel,
    const float* __restrict__ g2, const float* __restrict__ v2,
    const float* __restrict__ g3, const float* __restrict__ v3,
    unsigned short* __restrict__ wf, unsigned short* __restrict__ relB,
    unsigned short* __restrict__ relvA)
{
    if (blockIdx.x < 160) {
        int t = blockIdx.x * 256 + threadIdx.x;       // 0..40959
        int o  = t >> 6;
        int c0 = (t & 63) * 8;
        const float* src = w + (size_t)o * C_ + c0;
        u16x8 p;
#pragma unroll
        for (int e = 0; e < 8; ++e) p[e] = f2bf(src[e]);
        int f = (o >> 4) * 16 + (c0 >> 5);
        int l = (o & 15) | (((c0 >> 3) & 3) << 4);
        *reinterpret_cast<u16x8*>(&wf[(size_t)f * 512 + l * 8]) = p;
        return;
    }
    int tid = (blockIdx.x - 160) * 256 + threadIdx.x;
    if (tid < 4096) {                      // relB
        int h = tid >> 9, uf = (tid >> 6) & 7, l = tid & 63;
        int u = uf * 16 + (l & 15);
        int g = l >> 4;
        float sq = g2[3*h]     * rsqrtf(v2[3*h]     + EPS_);
        float sk = g2[3*h + 1] * rsqrtf(v2[3*h + 1] + EPS_);
        u16x8 p;
#pragma unroll
        for (int e = 0; e < 8; ++e) {
            int s = g * 8 + e;
            float val = 0.f;
            if (u < 127 && s < 16)
                val = (s < 8 ? sq : sk) * rel[s * 127 + u];
            p[e] = f2bf(val);
        }
        *reinterpret_cast<u16x8*>(&relB[(size_t)tid * 8]) = p;
    } else if (tid < 4096 + 8192) {        // relvA
        int t2 = tid - 4096;
        int h = t2 >> 10, iF = (t2 >> 8) & 3, tt = (t2 >> 6) & 3, l = t2 & 63;
        int i = iF * 16 + (l & 15);
        int c3 = h * 64 + i;
        float scl = g3[c3] * rsqrtf(v3[c3] + EPS_);
        const float* rrow = rel + (size_t)(16 + i) * 127;
        u16x8 p;
#pragma unroll
        for (int e = 0; e < 8; ++e) {
            int u = (l >> 4) * 8 + e + 32 * tt;
            p[e] = f2bf((u < 127) ? scl * rrow[u] : 0.f);
        }
        *reinterpret_cast<u16x8*>(&relvA[(size_t)t2 * 8]) = p;
    }
}

// ---------------------------------------------------------------------------
// K1 v13 = v7 semantics (KBAR, BK=64, af 10-frag pipeline, compact qkA) at
// HALF BLOCK SIZE: 256 thr / 4 waves, 2048 blocks (b x M-half of 320 rows).
// Regs ~188 -> 2 waves/SIMD -> TWO independent blocks per CU: when one
// block's waves sit at KBAR, the other block's waves keep issuing MFMA
// (m114 inter-block overlap — the thing a single lockstep block can't do).
// Cost: x read twice (HBM at 19%, headroom). Tripwire: k1>=105 -> revert.
// ---------------------------------------------------------------------------
#define LDW1 72   // bf16 row stride: 144 B

struct K1Ctx {
    const float* xb;
    const unsigned short* wf;    // wf + mh*20*16*512 (M-half base)
    unsigned short (*xt)[64 * LDW1];
    int wv, lane, lm, lg, cp, c4;
};

template<int KT>
__device__ __forceinline__ void k1_step(const K1Ctx& c, f32x4 (&acc)[5][4],
                                        bf16x8 (&afu)[10], bf16x8 (&afp)[10])
{
    if (KT < 7) {
#pragma unroll
        for (int i = 0; i < 10; ++i) {
            int fm = i % 5, ks = i / 5;
            size_t f = (size_t)((c.wv * 5 + fm) * 16 + (KT + 1) * 2 + ks) * 512;
            afp[i] = *reinterpret_cast<const bf16x8*>(&c.wf[f + c.lane * 8]);
        }
    }
    f32x4 pa, pc, pa2, pc2;
    if (KT < 7) {
        pa  = *reinterpret_cast<const f32x4*>(&c.xb[((KT + 1) * 64 + 2 * c.cp) * 64 + c.c4]);
        pc  = *reinterpret_cast<const f32x4*>(&c.xb[((KT + 1) * 64 + 2 * c.cp + 1) * 64 + c.c4]);
        pa2 = *reinterpret_cast<const f32x4*>(&c.xb[((KT + 1) * 64 + 2 * (c.cp + 16)) * 64 + c.c4]);
        pc2 = *reinterpret_cast<const f32x4*>(&c.xb[((KT + 1) * 64 + 2 * (c.cp + 16) + 1) * 64 + c.c4]);
    }
#pragma unroll
    for (int ks = 0; ks < 2; ++ks) {
        bf16x8 bfr[4];
#pragma unroll
        for (int fn = 0; fn < 4; ++fn)
            bfr[fn] = *reinterpret_cast<const bf16x8*>(
                &c.xt[KT & 1][(fn * 16 + c.lm) * LDW1 + ks * 32 + c.lg * 8]);
#pragma unroll
        for (int fm = 0; fm < 5; ++fm)
#pragma unroll
            for (int fn = 0; fn < 4; ++fn)
                acc[fm][fn] = __builtin_amdgcn_mfma_f32_16x16x32_bf16(
                    afu[ks * 5 + fm], bfr[fn], acc[fm][fn], 0, 0, 0);
    }
    if (KT < 7) {
#pragma unroll
        for (int j = 0; j < 4; ++j) {
            unsigned int pk = (unsigned int)f2bf(pa[j]) | ((unsigned int)f2bf(pc[j]) << 16);
            *reinterpret_cast<unsigned int*>(
                &c.xt[(KT & 1) ^ 1][(c.c4 + j) * LDW1 + 2 * c.cp]) = pk;
            unsigned int pk2 = (unsigned int)f2bf(pa2[j]) | ((unsigned int)f2bf(pc2[j]) << 16);
            *reinterpret_cast<unsigned int*>(
                &c.xt[(KT & 1) ^ 1][(c.c4 + j) * LDW1 + 2 * (c.cp + 16)]) = pk2;
        }
    }
    KBAR();
}

__global__ __launch_bounds__(256) void k1_gemm(
    const float* __restrict__ x, const unsigned short* __restrict__ wf,
    const float* __restrict__ g1, const float* __restrict__ b1,
    const float* __restrict__ m1, const float* __restrict__ v1,
    const float* __restrict__ g3, const float* __restrict__ v3,
    unsigned short* __restrict__ qkA, unsigned short* __restrict__ vB)
{
    __shared__ unsigned short xt[2][64 * LDW1];   // 2 x 9216 B
    __shared__ float ssc[320], ssh[320];

    const int tid  = threadIdx.x;
    const int b    = blockIdx.x >> 1;
    const int mh   = blockIdx.x & 1;
    const int row0 = mh * 320;

    for (int t = tid; t < 320; t += 256) {
        int o = row0 + t;
        float sc = g1[o] * rsqrtf(v1[o] + EPS_);
        float sh = b1[o] - m1[o] * sc;
        int cc = o >> 3, hh = o & 7;
        if (cc >= 16) {                        // fold BN3 sc_o into v
            int c3 = 512 + hh * 64 + (cc - 16);
            float f = g3[c3] * rsqrtf(v3[c3] + EPS_);
            sc *= f; sh *= f;
        }
        ssc[t] = sc;
        ssh[t] = sh;
    }

    K1Ctx c;
    c.xb   = x + (size_t)b * C_ * D_;
    c.wf   = wf + (size_t)(mh * 20) * 16 * 512;
    c.xt   = xt;
    c.lane = tid & 63;
    c.wv   = tid >> 6;            // 0..3
    c.lm   = c.lane & 15;
    c.lg   = c.lane >> 4;
    c.cp   = tid >> 4;            // 0..15 (handles c-pairs cp and cp+16)
    c.c4   = (tid & 15) * 4;

    f32x4 acc[5][4];
#pragma unroll
    for (int i = 0; i < 5; ++i)
#pragma unroll
        for (int j = 0; j < 4; ++j) acc[i][j] = (f32x4){0.f, 0.f, 0.f, 0.f};

    bf16x8 afA[10], afB[10];
#pragma unroll
    for (int i = 0; i < 10; ++i) {
        int fm = i % 5, ks = i / 5;
        size_t f = (size_t)((c.wv * 5 + fm) * 16 + ks) * 512;
        afA[i] = *reinterpret_cast<const bf16x8*>(&c.wf[f + c.lane * 8]);
    }
    {   // prologue: stage x tile 0 into buf 0 (both c-pair halves)
        f32x4 a  = *reinterpret_cast<const f32x4*>(&c.xb[(2 * c.cp) * 64 + c.c4]);
        f32x4 d  = *reinterpret_cast<const f32x4*>(&c.xb[(2 * c.cp + 1) * 64 + c.c4]);
        f32x4 a2 = *reinterpret_cast<const f32x4*>(&c.xb[(2 * (c.cp + 16)) * 64 + c.c4]);
        f32x4 d2 = *reinterpret_cast<const f32x4*>(&c.xb[(2 * (c.cp + 16) + 1) * 64 + c.c4]);
#pragma unroll
        for (int j = 0; j < 4; ++j) {
            unsigned int pk = (unsigned int)f2bf(a[j]) | ((unsigned int)f2bf(d[j]) << 16);
            *reinterpret_cast<unsigned int*>(&xt[0][(c.c4 + j) * LDW1 + 2 * c.cp]) = pk;
            unsigned int pk2 = (unsigned int)f2bf(a2[j]) | ((unsigned int)f2bf(d2[j]) << 16);
            *reinterpret_cast<unsigned int*>(&xt[0][(c.c4 + j) * LDW1 + 2 * (c.cp + 16)]) = pk2;
        }
    }
    KBAR();

    k1_step<0>(c, acc, afA, afB);
    k1_step<1>(c, acc, afB, afA);
    k1_step<2>(c, acc, afA, afB);
    k1_step<3>(c, acc, afB, afA);
    k1_step<4>(c, acc, afA, afB);
    k1_step<5>(c, acc, afB, afA);
    k1_step<6>(c, acc, afA, afB);
    k1_step<7>(c, acc, afB, afA);

    // epilogue: BN1 (+folded BN3 for v), scatter. qkA compact (stride 256).
    const int wv = c.wv, lm = c.lm, lg = c.lg;
#pragma unroll
    for (int fm = 0; fm < 5; ++fm) {
#pragma unroll
        for (int fn = 0; fn < 4; ++fn) {
            int d = fn * 16 + lm;
#pragma unroll
            for (int r = 0; r < 4; ++r) {
                int rl = wv * 80 + fm * 16 + lg * 4 + r;
                int o  = row0 + rl;
                int cc = o >> 3, hh = o & 7;
                float val = acc[fm][fn][r] * ssc[rl] + ssh[rl];
                unsigned short bv = f2bf(val);
                if (cc < 8)
                    qkA[(((size_t)b * 8 + hh) * 4 + (d >> 4)) * 256 + (d & 15) * 8 + cc] = bv;
                else if (cc < 16)
                    qkA[(((size_t)b * 8 + hh) * 4 + (d >> 4)) * 256 + ((d & 15) + 16) * 8 + (cc - 8)] = bv;
                else
                    vB[((size_t)(b * 8 + hh) * 64 + (cc - 16)) * 64 + d] = bv;
            }
        }
    }
}

// ---------------------------------------------------------------------------
// K2: round-17/19 kernel (band-skip phase 1, compact-qkA reads) — unchanged.
// ---------------------------------------------------------------------------
#define SGP 84    // SGb row stride (f32)
#define SA  72    // attn row stride (u16)
#define RLD 136   // A2 row stride (u16)

__global__ __launch_bounds__(256) void k2_attn(
    const unsigned short* __restrict__ qkA, const unsigned short* __restrict__ vB,
    const unsigned short* __restrict__ relB, const unsigned short* __restrict__ relvA,
    const float* __restrict__ g2, const float* __restrict__ v2,
    const float* __restrict__ g3, const float* __restrict__ b3,
    const float* __restrict__ m3, const float* __restrict__ v3,
    float* __restrict__ outp)
{
    __shared__ float          SGb[64 * SGP];   // 21504 B
    __shared__ unsigned short attn[64 * SA];   // 9216 B
    __shared__ unsigned short A2[64 * RLD];    // 17408 B
    __shared__ float sh3[64];

    const int tid  = threadIdx.x;
    const int b    = blockIdx.x >> 3;
    const int h    = blockIdx.x & 7;
    const int lane = tid & 63;
    const int w    = tid >> 6;
    const int lmm  = lane & 15;
    const int lg   = lane >> 4;

    const unsigned short* qbase = qkA + ((size_t)(b * 8 + h) * 4) * 256;

    for (int i = tid; i < 64 * RLD / 2; i += 256)
        reinterpret_cast<unsigned int*>(A2)[i] = 0u;
    if (tid < 64) {
        int c = h * 64 + tid;
        float sa = g3[c] * rsqrtf(v3[c] + EPS_);
        float sb = g3[512 + c] * rsqrtf(v3[512 + c] + EPS_);
        sh3[tid] = (b3[c] - m3[c] * sa) + (b3[512 + c] - m3[512 + c] * sb);
    }
    const float s_dt = g2[3 * h + 2] * rsqrtf(v2[3 * h + 2] + EPS_);

    // ---- phase 1: MFMA scores (band-skipped SG fragments) ----
    const int uf_lo = (w == 0) ? 0 : ((16 * w - 15) >> 4);
    const int uf_hi_raw = (16 * w + 78) >> 4;
    const int uf_hi = uf_hi_raw > 7 ? 7 : uf_hi_raw;

    bf16x8 zv = {0, 0, 0, 0, 0, 0, 0, 0};
    bf16x8 aA = zv;
    if (lane < 32)
        aA = *reinterpret_cast<const bf16x8*>(&qbase[w * 256 + lane * 8]);
    bf16x8 kBf[4];
#pragma unroll
    for (int jf = 0; jf < 4; ++jf) {
        kBf[jf] = zv;
        if (lane < 16)
            kBf[jf] = *reinterpret_cast<const bf16x8*>(&qbase[jf * 256 + (lane + 16) * 8]);
    }
    bf16x8 rBf[8];
#pragma unroll
    for (int uf = 0; uf < 8; ++uf) {
        rBf[uf] = zv;
        if (uf >= uf_lo && uf <= uf_hi)
            rBf[uf] = *reinterpret_cast<const bf16x8*>(
                &relB[(size_t)(h * 8 + uf) * 512 + lane * 8]);
    }

    f32x4 dotsAcc[4];
#pragma unroll
    for (int jf = 0; jf < 4; ++jf)
        dotsAcc[jf] = __builtin_amdgcn_mfma_f32_16x16x32_bf16(
            aA, kBf[jf], (f32x4){0.f, 0.f, 0.f, 0.f}, 0, 0, 0);
    f32x4 sgAcc[8];
#pragma unroll
    for (int uf = 0; uf < 8; ++uf) {
        sgAcc[uf] = (f32x4){0.f, 0.f, 0.f, 0.f};
        if (uf >= uf_lo && uf <= uf_hi)
            sgAcc[uf] = __builtin_amdgcn_mfma_f32_16x16x32_bf16(
                aA, rBf[uf], sgAcc[uf], 0, 0, 0);
    }

    // write SGb (f32 band): row d = w*16 + lg*4 + r, t = u - d + 15
#pragma unroll
    for (int uf = 0; uf < 8; ++uf) {
        if (uf < uf_lo || uf > uf_hi) continue;
#pragma unroll
        for (int r = 0; r < 4; ++r) {
            int d = (w << 4) + (lg << 2) + r;
            int t = uf * 16 + lmm - d + 15;
            if (t >= 0 && t < 79)
                SGb[d * SGP + t] = sgAcc[uf][r];
        }
    }
    __syncthreads();

    // ---- phase 2: softmax (row d across 16 lanes of the lg-group) ----
#pragma unroll
    for (int r = 0; r < 4; ++r) {
        int d = (w << 4) + (lg << 2) + r;
        const float* sgr = &SGb[d * SGP];
        float sc0 = s_dt * dotsAcc[0][r] + sgr[78 - lmm];
        float sc1 = s_dt * dotsAcc[1][r] + sgr[62 - lmm];
        float sc2 = s_dt * dotsAcc[2][r] + sgr[46 - lmm];
        float sc3 = s_dt * dotsAcc[3][r] + sgr[30 - lmm];
        float mx = fmaxf(fmaxf(sc0, sc1), fmaxf(sc2, sc3));
        mx = fmaxf(mx, __shfl_xor(mx, 1));
        mx = fmaxf(mx, __shfl_xor(mx, 2));
        mx = fmaxf(mx, __shfl_xor(mx, 4));
        mx = fmaxf(mx, __shfl_xor(mx, 8));
        float e0 = __expf(sc0 - mx), e1 = __expf(sc1 - mx);
        float e2 = __expf(sc2 - mx), e3 = __expf(sc3 - mx);
        float sum = (e0 + e1) + (e2 + e3);
        sum += __shfl_xor(sum, 1);
        sum += __shfl_xor(sum, 2);
        sum += __shfl_xor(sum, 4);
        sum += __shfl_xor(sum, 8);
        float inv = 1.f / sum;
        unsigned short p0 = f2bf(e0 * inv), p1 = f2bf(e1 * inv);
        unsigned short p2 = f2bf(e2 * inv), p3 = f2bf(e3 * inv);
        attn[d * SA + lmm]      = p0;
        attn[d * SA + 16 + lmm] = p1;
        attn[d * SA + 32 + lmm] = p2;
        attn[d * SA + 48 + lmm] = p3;
        A2[d * RLD + 63 + d - lmm] = p0;
        A2[d * RLD + 47 + d - lmm] = p1;
        A2[d * RLD + 31 + d - lmm] = p2;
        A2[d * RLD + 15 + d - lmm] = p3;
    }

    // ---- phase-3 A-fragment loads (global; land during barrier) ----
    const int lk8  = lg * 8;
    const int irow = (w << 4) + lmm;
    const unsigned short* vbase = vB + (size_t)(b * 8 + h) * 4096;
    bf16x8 av0 = *reinterpret_cast<const bf16x8*>(&vbase[irow * 64 + lk8]);
    bf16x8 av1 = *reinterpret_cast<const bf16x8*>(&vbase[irow * 64 + 32 + lk8]);
    bf16x8 rvA[4];
#pragma unroll
    for (int t = 0; t < 4; ++t)
        rvA[t] = *reinterpret_cast<const bf16x8*>(
            &relvA[(size_t)(((h * 4 + w) * 4 + t)) * 512 + lane * 8]);

    __syncthreads();

    // ---- phase 3: MFMA out + kv ----
    f32x4 acc[4];
#pragma unroll
    for (int nf = 0; nf < 4; ++nf) acc[nf] = (f32x4){0.f, 0.f, 0.f, 0.f};

#pragma unroll
    for (int nf = 0; nf < 4; ++nf) {
        const unsigned short* arow = &attn[(nf * 16 + lmm) * SA + lk8];
        acc[nf] = __builtin_amdgcn_mfma_f32_16x16x32_bf16(
            av0, *reinterpret_cast<const bf16x8*>(&arow[0]), acc[nf], 0, 0, 0);
        acc[nf] = __builtin_amdgcn_mfma_f32_16x16x32_bf16(
            av1, *reinterpret_cast<const bf16x8*>(&arow[32]), acc[nf], 0, 0, 0);
        const unsigned short* a2row = &A2[(nf * 16 + lmm) * RLD + lk8];
        acc[nf] = __builtin_amdgcn_mfma_f32_16x16x32_bf16(
            rvA[0], *reinterpret_cast<const bf16x8*>(&a2row[0]), acc[nf], 0, 0, 0);
        acc[nf] = __builtin_amdgcn_mfma_f32_16x16x32_bf16(
            rvA[1], *reinterpret_cast<const bf16x8*>(&a2row[32]), acc[nf], 0, 0, 0);
        acc[nf] = __builtin_amdgcn_mfma_f32_16x16x32_bf16(
            rvA[2], *reinterpret_cast<const bf16x8*>(&a2row[64]), acc[nf], 0, 0, 0);
        acc[nf] = __builtin_amdgcn_mfma_f32_16x16x32_bf16(
            rvA[3], *reinterpret_cast<const bf16x8*>(&a2row[96]), acc[nf], 0, 0, 0);
    }

    // ---- epilogue ----
    float* op = outp + ((size_t)b * 512 + h * 64) * 64;
    const int r0 = lg * 4;
#pragma unroll
    for (int r = 0; r < 4; ++r) {
        int i = (w << 4) + r0 + r;
        float sh = sh3[i];
#pragma unroll
        for (int nf = 0; nf < 4; ++nf)
            op[(size_t)i * 64 + nf * 16 + lmm] = acc[nf][r] + sh;
    }
}

extern "C" void kernel_launch(void* const* d_in, const int* in_sizes, int n_in,
                              void* d_out, int out_size, void* d_ws, size_t ws_size,
                              hipStream_t stream) {
    (void)in_sizes; (void)n_in; (void)out_size; (void)ws_size;
    const float* x   = (const float*)d_in[0];
    const float* w   = (const float*)d_in[1];
    const float* g1  = (const float*)d_in[2];
    const float* b1  = (const float*)d_in[3];
    const float* m1  = (const float*)d_in[4];
    const float* v1  = (const float*)d_in[5];
    const float* rel = (const float*)d_in[6];
    const float* g2  = (const float*)d_in[7];
    const float* b2  = (const float*)d_in[8];  (void)b2;
    const float* m2  = (const float*)d_in[9];  (void)m2;
    const float* v2  = (const float*)d_in[10];
    const float* g3  = (const float*)d_in[11];
    const float* b3  = (const float*)d_in[12];
    const float* m3  = (const float*)d_in[13];
    const float* v3  = (const float*)d_in[14];
    float* out = (float*)d_out;

    // ws: wf 640KB | relB 64KB | relvA 128KB | pad | qkA 16.8MB | vB 64MB
    unsigned short* wfrag = (unsigned short*)d_ws;
    unsigned short* relB  = (unsigned short*)((char*)d_ws + 655360);
    unsigned short* relvA = (unsigned short*)((char*)d_ws + 720896);
    unsigned short* qkA   = (unsigned short*)((char*)d_ws + 1048576);
    unsigned short* vB    = (unsigned short*)((char*)d_ws + 1048576 + (size_t)16777216);

    hipLaunchKernelGGL(k0_prep, dim3(208), dim3(256), 0, stream,
                       w, rel, g2, v2, g3, v3, wfrag, relB, relvA);
    hipLaunchKernelGGL(k1_gemm, dim3(2048), dim3(256), 0, stream,
                       x, wfrag, g1, b1, m1, v1, g3, v3, qkA, vB);
    hipLaunchKernelGGL(k2_attn, dim3(8192), dim3(256), 0, stream,
                       qkA, vB, relB, relvA, g2, v2, g3, b3, m3, v3, out);
}

// Round 21
// 163.901 us; speedup vs baseline: 1.1150x; 1.1150x over previous
//
#include <hip/hip_runtime.h>
#include <hip/hip_bf16.h>

#define B_    1024
#define C_    512
#define H_    8
#define D_    64
#define EPS_  1e-5f

typedef __attribute__((ext_vector_type(4))) float f32x4;
typedef __attribute__((ext_vector_type(8))) short bf16x8;
typedef __attribute__((ext_vector_type(8))) unsigned short u16x8;

__device__ __forceinline__ float bf2f(unsigned short h) {
    union { unsigned int u; float f; } c;
    c.u = ((unsigned int)h) << 16;
    return c.f;
}
__device__ __forceinline__ unsigned short f2bf(float f) {
    __hip_bfloat16 h = __float2bfloat16(f);
    return *reinterpret_cast<unsigned short*>(&h);
}

// LDS-only barrier: order ds ops across waves WITHOUT draining vmcnt.
#define KBAR() do { \
    asm volatile("s_waitcnt lgkmcnt(0)" ::: "memory"); \
    __builtin_amdgcn_s_barrier(); \
} while (0)

// ---------------------------------------------------------------------------
// K0 (merged): blocks 0..159 convert conv_w -> bf16 A-fragment order;
// blocks 160..207 build relB / relvA tables. Saves one launch.
// ---------------------------------------------------------------------------
__global__ __launch_bounds__(256) void k0_prep(
    const float* __restrict__ w, const float* __restrict__ rel,
    const float* __restrict__ g2, const float* __restrict__ v2,
    const float* __restrict__ g3, const float* __restrict__ v3,
    unsigned short* __restrict__ wf, unsigned short* __restrict__ relB,
    unsigned short* __restrict__ relvA)
{
    if (blockIdx.x < 160) {
        int t = blockIdx.x * 256 + threadIdx.x;       // 0..40959
        int o  = t >> 6;
        int c0 = (t & 63) * 8;
        const float* src = w + (size_t)o * C_ + c0;
        u16x8 p;
#pragma unroll
        for (int e = 0; e < 8; ++e) p[e] = f2bf(src[e]);
        int f = (o >> 4) * 16 + (c0 >> 5);
        int l = (o & 15) | (((c0 >> 3) & 3) << 4);
        *reinterpret_cast<u16x8*>(&wf[(size_t)f * 512 + l * 8]) = p;
        return;
    }
    int tid = (blockIdx.x - 160) * 256 + threadIdx.x;
    if (tid < 4096) {                      // relB
        int h = tid >> 9, uf = (tid >> 6) & 7, l = tid & 63;
        int u = uf * 16 + (l & 15);
        int g = l >> 4;
        float sq = g2[3*h]     * rsqrtf(v2[3*h]     + EPS_);
        float sk = g2[3*h + 1] * rsqrtf(v2[3*h + 1] + EPS_);
        u16x8 p;
#pragma unroll
        for (int e = 0; e < 8; ++e) {
            int s = g * 8 + e;
            float val = 0.f;
            if (u < 127 && s < 16)
                val = (s < 8 ? sq : sk) * rel[s * 127 + u];
            p[e] = f2bf(val);
        }
        *reinterpret_cast<u16x8*>(&relB[(size_t)tid * 8]) = p;
    } else if (tid < 4096 + 8192) {        // relvA
        int t2 = tid - 4096;
        int h = t2 >> 10, iF = (t2 >> 8) & 3, tt = (t2 >> 6) & 3, l = t2 & 63;
        int i = iF * 16 + (l & 15);
        int c3 = h * 64 + i;
        float scl = g3[c3] * rsqrtf(v3[c3] + EPS_);
        const float* rrow = rel + (size_t)(16 + i) * 127;
        u16x8 p;
#pragma unroll
        for (int e = 0; e < 8; ++e) {
            int u = (l >> 4) * 8 + e + 32 * tt;
            p[e] = f2bf((u < 127) ? scl * rrow[u] : 0.f);
        }
        *reinterpret_cast<u16x8*>(&relvA[(size_t)t2 * 8]) = p;
    }
}

// ---------------------------------------------------------------------------
// K1 = round-13 v7 (session best: ~107-108us). One block per b: M=640 N=64
// K=512, BK=64, dbuf LDS, KBAR loop barriers, wf A-frags pipelined 1 step
// ahead, compact qkA (stride 256).
// ---------------------------------------------------------------------------
#define LDW1 72   // bf16 row stride: 144 B

struct K1Ctx {
    const float* xb;
    const unsigned short* wf;
    unsigned short (*xt)[64 * LDW1];
    int wv, lane, lm, lg, cp, c4;
};

template<int KT>
__device__ __forceinline__ void k1_step(const K1Ctx& c, f32x4 (&acc)[5][4],
                                        bf16x8 (&afu)[10], bf16x8 (&afp)[10])
{
    if (KT < 7) {
#pragma unroll
        for (int i = 0; i < 10; ++i) {
            int fm = i % 5, ks = i / 5;
            size_t f = (size_t)((c.wv * 5 + fm) * 16 + (KT + 1) * 2 + ks) * 512;
            afp[i] = *reinterpret_cast<const bf16x8*>(&c.wf[f + c.lane * 8]);
        }
    }
    f32x4 pa, pc;
    if (KT < 7) {
        pa = *reinterpret_cast<const f32x4*>(&c.xb[((KT + 1) * 64 + 2 * c.cp) * 64 + c.c4]);
        pc = *reinterpret_cast<const f32x4*>(&c.xb[((KT + 1) * 64 + 2 * c.cp + 1) * 64 + c.c4]);
    }
#pragma unroll
    for (int ks = 0; ks < 2; ++ks) {
        bf16x8 bfr[4];
#pragma unroll
        for (int fn = 0; fn < 4; ++fn)
            bfr[fn] = *reinterpret_cast<const bf16x8*>(
                &c.xt[KT & 1][(fn * 16 + c.lm) * LDW1 + ks * 32 + c.lg * 8]);
#pragma unroll
        for (int fm = 0; fm < 5; ++fm)
#pragma unroll
            for (int fn = 0; fn < 4; ++fn)
                acc[fm][fn] = __builtin_amdgcn_mfma_f32_16x16x32_bf16(
                    afu[ks * 5 + fm], bfr[fn], acc[fm][fn], 0, 0, 0);
    }
    if (KT < 7) {
#pragma unroll
        for (int j = 0; j < 4; ++j) {
            unsigned int pk = (unsigned int)f2bf(pa[j]) | ((unsigned int)f2bf(pc[j]) << 16);
            *reinterpret_cast<unsigned int*>(
                &c.xt[(KT & 1) ^ 1][(c.c4 + j) * LDW1 + 2 * c.cp]) = pk;
        }
    }
    KBAR();
}

__global__ __launch_bounds__(512) void k1_gemm(
    const float* __restrict__ x, const unsigned short* __restrict__ wf,
    const float* __restrict__ g1, const float* __restrict__ b1,
    const float* __restrict__ m1, const float* __restrict__ v1,
    const float* __restrict__ g3, const float* __restrict__ v3,
    unsigned short* __restrict__ qkA, unsigned short* __restrict__ vB)
{
    __shared__ unsigned short xt[2][64 * LDW1];   // 2 x 9216 B
    __shared__ float ssc[640], ssh[640];

    const int tid = threadIdx.x;
    const int b   = blockIdx.x;

    for (int t = tid; t < 640; t += 512) {
        float sc = g1[t] * rsqrtf(v1[t] + EPS_);
        float sh = b1[t] - m1[t] * sc;
        int cc = t >> 3, hh = t & 7;
        if (cc >= 16) {                        // fold BN3 sc_o into v
            int c3 = 512 + hh * 64 + (cc - 16);
            float f = g3[c3] * rsqrtf(v3[c3] + EPS_);
            sc *= f; sh *= f;
        }
        ssc[t] = sc;
        ssh[t] = sh;
    }

    K1Ctx c;
    c.xb   = x + (size_t)b * C_ * D_;
    c.wf   = wf;
    c.xt   = xt;
    c.lane = tid & 63;
    c.wv   = tid >> 6;
    c.lm   = c.lane & 15;
    c.lg   = c.lane >> 4;
    c.cp   = tid >> 4;
    c.c4   = (tid & 15) * 4;

    f32x4 acc[5][4];
#pragma unroll
    for (int i = 0; i < 5; ++i)
#pragma unroll
        for (int j = 0; j < 4; ++j) acc[i][j] = (f32x4){0.f, 0.f, 0.f, 0.f};

    bf16x8 afA[10], afB[10];
#pragma unroll
    for (int i = 0; i < 10; ++i) {
        int fm = i % 5, ks = i / 5;
        size_t f = (size_t)((c.wv * 5 + fm) * 16 + ks) * 512;
        afA[i] = *reinterpret_cast<const bf16x8*>(&wf[f + c.lane * 8]);
    }
    {
        f32x4 a = *reinterpret_cast<const f32x4*>(&c.xb[(2 * c.cp) * 64 + c.c4]);
        f32x4 d = *reinterpret_cast<const f32x4*>(&c.xb[(2 * c.cp + 1) * 64 + c.c4]);
#pragma unroll
        for (int j = 0; j < 4; ++j) {
            unsigned int pk = (unsigned int)f2bf(a[j]) | ((unsigned int)f2bf(d[j]) << 16);
            *reinterpret_cast<unsigned int*>(&xt[0][(c.c4 + j) * LDW1 + 2 * c.cp]) = pk;
        }
    }
    KBAR();

    k1_step<0>(c, acc, afA, afB);
    k1_step<1>(c, acc, afB, afA);
    k1_step<2>(c, acc, afA, afB);
    k1_step<3>(c, acc, afB, afA);
    k1_step<4>(c, acc, afA, afB);
    k1_step<5>(c, acc, afB, afA);
    k1_step<6>(c, acc, afA, afB);
    k1_step<7>(c, acc, afB, afA);

    const int wv = c.wv, lm = c.lm, lg = c.lg;
#pragma unroll
    for (int fm = 0; fm < 5; ++fm) {
#pragma unroll
        for (int fn = 0; fn < 4; ++fn) {
            int d = fn * 16 + lm;
#pragma unroll
            for (int r = 0; r < 4; ++r) {
                int o = wv * 80 + fm * 16 + lg * 4 + r;
                int cc = o >> 3, hh = o & 7;
                float val = acc[fm][fn][r] * ssc[o] + ssh[o];
                unsigned short bv = f2bf(val);
                if (cc < 8)
                    qkA[(((size_t)b * 8 + hh) * 4 + (d >> 4)) * 256 + (d & 15) * 8 + cc] = bv;
                else if (cc < 16)
                    qkA[(((size_t)b * 8 + hh) * 4 + (d >> 4)) * 256 + ((d & 15) + 16) * 8 + (cc - 8)] = bv;
                else
                    vB[((size_t)(b * 8 + hh) * 64 + (cc - 16)) * 64 + d] = bv;
            }
        }
    }
}

// ---------------------------------------------------------------------------
// K2: round-17/19 kernel (band-skip phase 1, compact-qkA reads).
// ---------------------------------------------------------------------------
#define SGP 84    // SGb row stride (f32)
#define SA  72    // attn row stride (u16)
#define RLD 136   // A2 row stride (u16)

__global__ __launch_bounds__(256) void k2_attn(
    const unsigned short* __restrict__ qkA, const unsigned short* __restrict__ vB,
    const unsigned short* __restrict__ relB, const unsigned short* __restrict__ relvA,
    const float* __restrict__ g2, const float* __restrict__ v2,
    const float* __restrict__ g3, const float* __restrict__ b3,
    const float* __restrict__ m3, const float* __restrict__ v3,
    float* __restrict__ outp)
{
    __shared__ float          SGb[64 * SGP];   // 21504 B
    __shared__ unsigned short attn[64 * SA];   // 9216 B
    __shared__ unsigned short A2[64 * RLD];    // 17408 B
    __shared__ float sh3[64];

    const int tid  = threadIdx.x;
    const int b    = blockIdx.x >> 3;
    const int h    = blockIdx.x & 7;
    const int lane = tid & 63;
    const int w    = tid >> 6;
    const int lmm  = lane & 15;
    const int lg   = lane >> 4;

    const unsigned short* qbase = qkA + ((size_t)(b * 8 + h) * 4) * 256;

    for (int i = tid; i < 64 * RLD / 2; i += 256)
        reinterpret_cast<unsigned int*>(A2)[i] = 0u;
    if (tid < 64) {
        int c = h * 64 + tid;
        float sa = g3[c] * rsqrtf(v3[c] + EPS_);
        float sb = g3[512 + c] * rsqrtf(v3[512 + c] + EPS_);
        sh3[tid] = (b3[c] - m3[c] * sa) + (b3[512 + c] - m3[512 + c] * sb);
    }
    const float s_dt = g2[3 * h + 2] * rsqrtf(v2[3 * h + 2] + EPS_);

    // ---- phase 1: MFMA scores (band-skipped SG fragments) ----
    const int uf_lo = (w == 0) ? 0 : ((16 * w - 15) >> 4);
    const int uf_hi_raw = (16 * w + 78) >> 4;
    const int uf_hi = uf_hi_raw > 7 ? 7 : uf_hi_raw;

    bf16x8 zv = {0, 0, 0, 0, 0, 0, 0, 0};
    bf16x8 aA = zv;
    if (lane < 32)
        aA = *reinterpret_cast<const bf16x8*>(&qbase[w * 256 + lane * 8]);
    bf16x8 kBf[4];
#pragma unroll
    for (int jf = 0; jf < 4; ++jf) {
        kBf[jf] = zv;
        if (lane < 16)
            kBf[jf] = *reinterpret_cast<const bf16x8*>(&qbase[jf * 256 + (lane + 16) * 8]);
    }
    bf16x8 rBf[8];
#pragma unroll
    for (int uf = 0; uf < 8; ++uf) {
        rBf[uf] = zv;
        if (uf >= uf_lo && uf <= uf_hi)
            rBf[uf] = *reinterpret_cast<const bf16x8*>(
                &relB[(size_t)(h * 8 + uf) * 512 + lane * 8]);
    }

    f32x4 dotsAcc[4];
#pragma unroll
    for (int jf = 0; jf < 4; ++jf)
        dotsAcc[jf] = __builtin_amdgcn_mfma_f32_16x16x32_bf16(
            aA, kBf[jf], (f32x4){0.f, 0.f, 0.f, 0.f}, 0, 0, 0);
    f32x4 sgAcc[8];
#pragma unroll
    for (int uf = 0; uf < 8; ++uf) {
        sgAcc[uf] = (f32x4){0.f, 0.f, 0.f, 0.f};
        if (uf >= uf_lo && uf <= uf_hi)
            sgAcc[uf] = __builtin_amdgcn_mfma_f32_16x16x32_bf16(
                aA, rBf[uf], sgAcc[uf], 0, 0, 0);
    }

    // write SGb (f32 band): row d = w*16 + lg*4 + r, t = u - d + 15
#pragma unroll
    for (int uf = 0; uf < 8; ++uf) {
        if (uf < uf_lo || uf > uf_hi) continue;
#pragma unroll
        for (int r = 0; r < 4; ++r) {
            int d = (w << 4) + (lg << 2) + r;
            int t = uf * 16 + lmm - d + 15;
            if (t >= 0 && t < 79)
                SGb[d * SGP + t] = sgAcc[uf][r];
        }
    }
    __syncthreads();

    // ---- phase 2: softmax (row d across 16 lanes of the lg-group) ----
#pragma unroll
    for (int r = 0; r < 4; ++r) {
        int d = (w << 4) + (lg << 2) + r;
        const float* sgr = &SGb[d * SGP];
        float sc0 = s_dt * dotsAcc[0][r] + sgr[78 - lmm];
        float sc1 = s_dt * dotsAcc[1][r] + sgr[62 - lmm];
        float sc2 = s_dt * dotsAcc[2][r] + sgr[46 - lmm];
        float sc3 = s_dt * dotsAcc[3][r] + sgr[30 - lmm];
        float mx = fmaxf(fmaxf(sc0, sc1), fmaxf(sc2, sc3));
        mx = fmaxf(mx, __shfl_xor(mx, 1));
        mx = fmaxf(mx, __shfl_xor(mx, 2));
        mx = fmaxf(mx, __shfl_xor(mx, 4));
        mx = fmaxf(mx, __shfl_xor(mx, 8));
        float e0 = __expf(sc0 - mx), e1 = __expf(sc1 - mx);
        float e2 = __expf(sc2 - mx), e3 = __expf(sc3 - mx);
        float sum = (e0 + e1) + (e2 + e3);
        sum += __shfl_xor(sum, 1);
        sum += __shfl_xor(sum, 2);
        sum += __shfl_xor(sum, 4);
        sum += __shfl_xor(sum, 8);
        float inv = 1.f / sum;
        unsigned short p0 = f2bf(e0 * inv), p1 = f2bf(e1 * inv);
        unsigned short p2 = f2bf(e2 * inv), p3 = f2bf(e3 * inv);
        attn[d * SA + lmm]      = p0;
        attn[d * SA + 16 + lmm] = p1;
        attn[d * SA + 32 + lmm] = p2;
        attn[d * SA + 48 + lmm] = p3;
        A2[d * RLD + 63 + d - lmm] = p0;
        A2[d * RLD + 47 + d - lmm] = p1;
        A2[d * RLD + 31 + d - lmm] = p2;
        A2[d * RLD + 15 + d - lmm] = p3;
    }

    // ---- phase-3 A-fragment loads (global; land during barrier) ----
    const int lk8  = lg * 8;
    const int irow = (w << 4) + lmm;
    const unsigned short* vbase = vB + (size_t)(b * 8 + h) * 4096;
    bf16x8 av0 = *reinterpret_cast<const bf16x8*>(&vbase[irow * 64 + lk8]);
    bf16x8 av1 = *reinterpret_cast<const bf16x8*>(&vbase[irow * 64 + 32 + lk8]);
    bf16x8 rvA[4];
#pragma unroll
    for (int t = 0; t < 4; ++t)
        rvA[t] = *reinterpret_cast<const bf16x8*>(
            &relvA[(size_t)(((h * 4 + w) * 4 + t)) * 512 + lane * 8]);

    __syncthreads();

    // ---- phase 3: MFMA out + kv ----
    f32x4 acc[4];
#pragma unroll
    for (int nf = 0; nf < 4; ++nf) acc[nf] = (f32x4){0.f, 0.f, 0.f, 0.f};

#pragma unroll
    for (int nf = 0; nf < 4; ++nf) {
        const unsigned short* arow = &attn[(nf * 16 + lmm) * SA + lk8];
        acc[nf] = __builtin_amdgcn_mfma_f32_16x16x32_bf16(
            av0, *reinterpret_cast<const bf16x8*>(&arow[0]), acc[nf], 0, 0, 0);
        acc[nf] = __builtin_amdgcn_mfma_f32_16x16x32_bf16(
            av1, *reinterpret_cast<const bf16x8*>(&arow[32]), acc[nf], 0, 0, 0);
        const unsigned short* a2row = &A2[(nf * 16 + lmm) * RLD + lk8];
        acc[nf] = __builtin_amdgcn_mfma_f32_16x16x32_bf16(
            rvA[0], *reinterpret_cast<const bf16x8*>(&a2row[0]), acc[nf], 0, 0, 0);
        acc[nf] = __builtin_amdgcn_mfma_f32_16x16x32_bf16(
            rvA[1], *reinterpret_cast<const bf16x8*>(&a2row[32]), acc[nf], 0, 0, 0);
        acc[nf] = __builtin_amdgcn_mfma_f32_16x16x32_bf16(
            rvA[2], *reinterpret_cast<const bf16x8*>(&a2row[64]), acc[nf], 0, 0, 0);
        acc[nf] = __builtin_amdgcn_mfma_f32_16x16x32_bf16(
            rvA[3], *reinterpret_cast<const bf16x8*>(&a2row[96]), acc[nf], 0, 0, 0);
    }

    // ---- epilogue ----
    float* op = outp + ((size_t)b * 512 + h * 64) * 64;
    const int r0 = lg * 4;
#pragma unroll
    for (int r = 0; r < 4; ++r) {
        int i = (w << 4) + r0 + r;
        float sh = sh3[i];
#pragma unroll
        for (int nf = 0; nf < 4; ++nf)
            op[(size_t)i * 64 + nf * 16 + lmm] = acc[nf][r] + sh;
    }
}

extern "C" void kernel_launch(void* const* d_in, const int* in_sizes, int n_in,
                              void* d_out, int out_size, void* d_ws, size_t ws_size,
                              hipStream_t stream) {
    (void)in_sizes; (void)n_in; (void)out_size; (void)ws_size;
    const float* x   = (const float*)d_in[0];
    const float* w   = (const float*)d_in[1];
    const float* g1  = (const float*)d_in[2];
    const float* b1  = (const float*)d_in[3];
    const float* m1  = (const float*)d_in[4];
    const float* v1  = (const float*)d_in[5];
    const float* rel = (const float*)d_in[6];
    const float* g2  = (const float*)d_in[7];
    const float* b2  = (const float*)d_in[8];  (void)b2;
    const float* m2  = (const float*)d_in[9];  (void)m2;
    const float* v2  = (const float*)d_in[10];
    const float* g3  = (const float*)d_in[11];
    const float* b3  = (const float*)d_in[12];
    const float* m3  = (const float*)d_in[13];
    const float* v3  = (const float*)d_in[14];
    float* out = (float*)d_out;

    // ws: wf 640KB | relB 64KB | relvA 128KB | pad | qkA 16.8MB | vB 64MB
    unsigned short* wfrag = (unsigned short*)d_ws;
    unsigned short* relB  = (unsigned short*)((char*)d_ws + 655360);
    unsigned short* relvA = (unsigned short*)((char*)d_ws + 720896);
    unsigned short* qkA   = (unsigned short*)((char*)d_ws + 1048576);
    unsigned short* vB    = (unsigned short*)((char*)d_ws + 1048576 + (size_t)16777216);

    hipLaunchKernelGGL(k0_prep, dim3(208), dim3(256), 0, stream,
                       w, rel, g2, v2, g3, v3, wfrag, relB, relvA);
    hipLaunchKernelGGL(k1_gemm, dim3(1024), dim3(512), 0, stream,
                       x, wfrag, g1, b1, m1, v1, g3, v3, qkA, vB);
    hipLaunchKernelGGL(k2_attn, dim3(8192), dim3(256), 0, stream,
                       qkA, vB, relB, relvA, g2, v2, g3, b3, m3, v3, out);
}